// Round 10
// baseline (126.217 us; speedup 1.0000x reference)
//
#include <hip/hip_runtime.h>

// EmbedDNF: B=128, IN_F=256, HID=512, OUT=128, E=8 (fp32, e innermost)
//
// impl = 1 - w*(1-xnor) = A + x*Bv ; A = 1 - w*s ; Bv = 2*w*s - w
// H[b,h,e]   = prod_i (A[i,h,e] + x[b,i,e]*Bv[i,h,e])
// out[b,o,e] = 1 - prod_h (1 - dw[h,o,e]*H[b,h,e])
//
// Laws (R4-R20): (1) acc <= 32 VGPR; (2) s1's LDS x-staging is load-bearing
// (R18: removing it -> 163 us); (3) no device-scope fences; (4) >= 4
// blocks/CU; s1 frozen at R14 (sum-of-pipes, no single binding term —
// R15/R16/R17/R18 all failed); (5) XCD-L2-pinning remaps are the proven
// lever family (R13 -2, R14 -5); (6) all stores must be >=32B line-clean
// (R18: 16B scatters -> 20x write amplification via write-allocate).
// Ledger (R19-confirmed): 88.6 = fill ~43 (harness poison, IN-WINDOW,
// untouchable — proven by s1 never ranking top-5) + s1 ~29 + s2 ~13 +
// comb2 ~3.
// This round (R20): s2 rebalance 8b x 1o -> 2b x 4o (P1 reads 64 -> 16 MB,
// the minimum) with R12's three failure causes individually fixed:
// all-256-thread prologue (1 float2 slot/thread, same left-fold product
// order), ks kept in LOW blockIdx bits (R13 pinning), line-clean gathers.
// dw cost rises 33 -> 134 MB but is 256 KB/XCD L2-resident. comb2: grid
// 128x256 -> 512x64. s1 byte-identical R14.
//
// ws: P1 [8][512][128][8] fp32 @ 0        (16 MB)  stage1 i-split partials
//     P2 [16][128][128][8] fp32 @ 4194304 (8 MB)   stage2 h-split partials

#define LD4(p) (*(const float4*)(p))
#define LD2(p) (*(const float2*)(p))

static __device__ __forceinline__ float4 f4mul(float4 a, float4 b) {
    return make_float4(a.x*b.x, a.y*b.y, a.z*b.z, a.w*b.w);
}
static __device__ __forceinline__ float4 f4fma(float4 a, float4 b, float4 c) {
    return make_float4(fmaf(a.x,b.x,c.x), fmaf(a.y,b.y,c.y),
                       fmaf(a.z,b.z,c.z), fmaf(a.w,b.w,c.w));
}
static __device__ __forceinline__ float4 f4nfma1(float4 d, float4 h) {  // 1-d*h
    return make_float4(fmaf(-d.x,h.x,1.0f), fmaf(-d.y,h.y,1.0f),
                       fmaf(-d.z,h.z,1.0f), fmaf(-d.w,h.w,1.0f));
}

// ---------------------------------------------------------------------------
// Stage 1 (R14, frozen). Grid 2048. Decode: bits [1:0]=hg-lo, [2]=ks-lo,
// [4:3]=hg-hi, [6:5]=ks-hi, [10:7]=bg. XCD = (hg&3)|(ks&1)<<2 -> hot cw/cs
// set 1 MB/XCD, 16x bg L2 reuse. Block 256 = 4 waves = 4 i-subchunks of 8.
// Lane = eh2 x hl32; thread tile 8b x 1h x 4e (acc = 32 VGPR).
// ---------------------------------------------------------------------------
__global__ __launch_bounds__(256, 4) void k_stage1(
    const float* __restrict__ in,   // [128][256][8]
    const float* __restrict__ cw,   // [256][512][8]
    const float* __restrict__ cs,   // [256][512][8]
    float* __restrict__ P1)         // ws: [8][512][128][8]
{
    __shared__ float lds[4096];              // 16 KB: x-tile [0,2048) then combine
    const int t    = threadIdx.x;
    const int lane = t & 63;
    const int kc   = t >> 6;                 // 0..3
    const int eh   = lane & 1;
    const int hl   = lane >> 1;              // 0..31
    const int bid  = blockIdx.x;
    const int hg   = (bid & 3) | (((bid >> 3) & 3) << 2);    // 0..15
    const int ks   = ((bid >> 2) & 1) | (((bid >> 5) & 3) << 1); // 0..7
    const int bg   = bid >> 7;                               // 0..15
    const int b0   = bg * 8;
    const int h    = hg * 32 + hl;
    const int e0   = eh * 4;

    // stage x[b0:+8][ks*32:+32][0:8] -> lds (layout [b][il][e]), coalesced
    {
        float4* xs4 = (float4*)lds;
        #pragma unroll
        for (int k = 0; k < 2; ++k) {
            const int f4  = t + k * 256;     // 0..511
            const int b   = f4 >> 6;
            const int col = f4 & 63;         // float4 within 256-float row
            xs4[f4] = LD4(in + (b0 + b) * 2048 + ks * 256 + col * 4);
        }
    }
    __syncthreads();

    const int i0 = ks * 32 + kc * 8;
    const float* pw = cw + i0 * 4096 + h * 8 + e0;
    const float* ps = cs + i0 * 4096 + h * 8 + e0;
    const float* xbase = lds + kc * 64 + e0;    // + b*256 + ii*8 (immediates)

    float4 acc[8];
    #pragma unroll
    for (int b = 0; b < 8; ++b) acc[b] = make_float4(1.f, 1.f, 1.f, 1.f);

    #pragma unroll
    for (int ii = 0; ii < 8; ++ii) {
        const float4 wv = LD4(pw);
        const float4 sv = LD4(ps);
        pw += 4096; ps += 4096;
        const float4 p  = f4mul(wv, sv);
        const float4 A  = make_float4(1.f - p.x, 1.f - p.y, 1.f - p.z, 1.f - p.w);
        const float4 Bv = make_float4(fmaf(2.f, p.x, -wv.x), fmaf(2.f, p.y, -wv.y),
                                      fmaf(2.f, p.z, -wv.z), fmaf(2.f, p.w, -wv.w));
        #pragma unroll
        for (int b = 0; b < 8; ++b) {
            const float4 xv = LD4(xbase + b * 256 + ii * 8);
            acc[b] = f4mul(acc[b], f4fma(xv, Bv, A));
        }
    }

    __syncthreads();                         // x-tile dead; reuse lds
    #pragma unroll
    for (int phase = 0; phase < 2; ++phase) {
        if (phase) __syncthreads();          // protect phase-0 reads
        #pragma unroll
        for (int j = 0; j < 4; ++j)
            *(float4*)&lds[kc * 1024 + j * 256 + hl * 8 + e0] = acc[phase * 4 + j];
        __syncthreads();
        {   // combine 4 kc; thread t -> one float4 of the 1024-float tile
            const int o4 = t * 4;            // j*256 + hl2*8 + eq*4
            float4 m = LD4(&lds[o4]);
            #pragma unroll
            for (int c = 1; c < 4; ++c) m = f4mul(m, LD4(&lds[c * 1024 + o4]));
            const int j   = o4 >> 8;
            const int hl2 = (o4 >> 3) & 31;
            const int eq  = o4 & 7;          // 0 or 4
            *(float4*)(P1 + ks * 524288 + (hg * 32 + hl2) * 1024
                          + (b0 + phase * 4 + j) * 8 + eq) = m;
        }
    }
}

// ---------------------------------------------------------------------------
// Stage 2 (R20 rebalance). Grid 1024 = ks16 (LOW bits: XCD = ks&7 pins P1
// h-slices + 256 KB dw slice in L2) x bg64 (b-pairs, high bits). Block 256
// = 4 waves = 4 h-subchunks of 8. Lane = eh2 x ol32; thread tile
// 2b x 4o x 4e (acc[4][2] = 32 VGPR). P1 read EXACTLY ONCE (16 MB total,
// the minimum; was 64 MB with og4).
// Prologue: H-tile [32h][2b][8e] = 512 floats; 256 threads x 1 float2-slot,
// 8 sequential P1-copy loads each (same left-fold order as before -> no fp
// grouping change), coalesced 8 B loads, NO idle threads (R12 fix #1).
// Step: 4 streaming dwordx4 (dw: 1 KB contiguous per wave-load, 4 o-quads)
// + 2 immediate-offset b128 broadcasts (2 b) + 64 VALU. 8 steps.
// Epilogue: 2 phases of 1 b via scratch LDS (line-clean 16 B stores into
// contiguous 4 KB runs, R12 fix #3). LDS 18 KB -> 4 blocks/CU.
// ---------------------------------------------------------------------------
__global__ __launch_bounds__(256, 4) void k_stage2(
    const float* __restrict__ dw,   // [512][128][8]
    const float* __restrict__ P1,   // ws: [8][512][128][8]
    float* __restrict__ P2)         // ws: [16][128][128][8]
{
    __shared__ float lds[4608];              // 18 KB: H [0,512) + scratch [512,4608)
    const int t    = threadIdx.x;
    const int lane = t & 63;
    const int kc   = t >> 6;                 // 0..3 (h-subchunk)
    const int eh   = lane & 1;
    const int ol   = lane >> 1;              // 0..31
    const int ks   = blockIdx.x & 15;        // LOW bits: XCD = ks&7 (R12 fix #2)
    const int bg   = blockIdx.x >> 4;        // 0..63
    const int b0   = bg * 2;
    const int e0   = eh * 4;
    const int h0   = ks * 32;

    // H-tile prologue: slot t = hl*8 + b*4 + ep -> H[hl][b][ep*2..+2].
    // 8 sequential copy loads (left-fold, order-identical to R13's).
    {
        const int hl = t >> 3;               // 0..31
        const int b  = (t >> 2) & 1;
        const int ep = t & 3;                // float2 within 8 e
        const float* q = P1 + (h0 + hl) * 1024 + (b0 + b) * 8 + ep * 2;
        float2 m = LD2(q);
        #pragma unroll
        for (int c = 1; c < 8; ++c) {
            const float2 v = LD2(q + c * 524288);
            m.x *= v.x; m.y *= v.y;
        }
        *(float2*)&lds[t * 2] = m;           // H at floats [hl*16 + b*8 + ep*2]
    }
    __syncthreads();

    const float* pd = dw + (h0 + kc * 8) * 1024 + ol * 8 + e0;
    // hv float4 at lds[(kc*8+ii)*16 + b*8 + eh*4] — ii,b immediates

    float4 acc[4][2];                        // [o-quad][b] = 32 VGPR
    #pragma unroll
    for (int q = 0; q < 4; ++q)
        #pragma unroll
        for (int b = 0; b < 2; ++b) acc[q][b] = make_float4(1.f, 1.f, 1.f, 1.f);

    #pragma unroll
    for (int ii = 0; ii < 8; ++ii) {
        const float4 dv0 = LD4(pd);
        const float4 dv1 = LD4(pd + 256);
        const float4 dv2 = LD4(pd + 512);
        const float4 dv3 = LD4(pd + 768);
        pd += 1024;
        const float4 hv0 = LD4(lds + (kc * 8 + ii) * 16 + eh * 4);      // b=0
        const float4 hv1 = LD4(lds + (kc * 8 + ii) * 16 + 8 + eh * 4);  // b=1
        acc[0][0] = f4mul(acc[0][0], f4nfma1(dv0, hv0));
        acc[1][0] = f4mul(acc[1][0], f4nfma1(dv1, hv0));
        acc[2][0] = f4mul(acc[2][0], f4nfma1(dv2, hv0));
        acc[3][0] = f4mul(acc[3][0], f4nfma1(dv3, hv0));
        acc[0][1] = f4mul(acc[0][1], f4nfma1(dv0, hv1));
        acc[1][1] = f4mul(acc[1][1], f4nfma1(dv1, hv1));
        acc[2][1] = f4mul(acc[2][1], f4nfma1(dv2, hv1));
        acc[3][1] = f4mul(acc[3][1], f4nfma1(dv3, hv1));
    }

    // kc-combine in scratch LDS [512,4608): 2 phases (phase = b).
    float* cmb = lds + 512;
    #pragma unroll
    for (int phase = 0; phase < 2; ++phase) {
        __syncthreads();                     // H-tile dead / protect prior reads
        #pragma unroll
        for (int q = 0; q < 4; ++q)
            *(float4*)&cmb[kc * 1024 + q * 256 + ol * 8 + e0] = acc[q][phase];
        __syncthreads();
        {   // combine 4 kc; thread t -> one float4 of the 1024-float tile
            const int o4 = t * 4;            // q*256 + ol2*8 + eq*4
            float4 m = LD4(&cmb[o4]);
            #pragma unroll
            for (int c = 1; c < 4; ++c) m = f4mul(m, LD4(&cmb[c * 1024 + o4]));
            const int q   = o4 >> 8;
            const int ol2 = (o4 >> 3) & 31;
            const int eq  = o4 & 7;          // 0 or 4
            *(float4*)(P2 + ks * 131072 + (b0 + phase) * 1024
                          + (q * 32 + ol2) * 8 + eq) = m;
        }
    }
}

// ---------------------------------------------------------------------------
// Final: out = 1 - prod over the 16 h-split partials. 8 MB read, 0.5 MB write.
// R20: grid 512 x 64 (was 128 x 256) — same work/thread, 4x block spread.
// ---------------------------------------------------------------------------
__global__ __launch_bounds__(64, 4) void k_comb2(
    const float* __restrict__ P2,   // ws: [16][128][128][8]
    float* __restrict__ out)        // [128][128][8]
{
    const int idx4 = blockIdx.x * 64 + threadIdx.x;    // 0..32767
    float4 m = LD4(P2 + idx4 * 4);
    #pragma unroll
    for (int c = 1; c < 16; ++c)
        m = f4mul(m, LD4(P2 + c * 131072 + idx4 * 4));
    const float4 r = make_float4(1.f - m.x, 1.f - m.y, 1.f - m.z, 1.f - m.w);
    *(float4*)(out + idx4 * 4) = r;
}

extern "C" void kernel_launch(void* const* d_in, const int* in_sizes, int n_in,
                              void* d_out, int out_size, void* d_ws, size_t ws_size,
                              hipStream_t stream)
{
    const float* in = (const float*)d_in[0];   // [128][256][8]
    const float* cw = (const float*)d_in[1];   // [256][512][8]
    const float* cs = (const float*)d_in[2];   // [256][512][8]
    const float* dw = (const float*)d_in[3];   // [512][128][8]
    float* outp = (float*)d_out;               // [128][128][8]
    float* P1   = (float*)d_ws;                // 16 MB
    float* P2   = (float*)d_ws + 4194304;      // 8 MB

    k_stage1<<<2048, 256, 0, stream>>>(in, cw, cs, P1);
    k_stage2<<<1024, 256, 0, stream>>>(dw, P1, P2);
    k_comb2<<<512, 64, 0, stream>>>(P2, outp);
}

// Round 11
// 88.520 us; speedup vs baseline: 1.4259x; 1.4259x over previous
//
#include <hip/hip_runtime.h>

// EmbedDNF: B=128, IN_F=256, HID=512, OUT=128, E=8 (fp32, e innermost)
//
// impl = 1 - w*(1-xnor) = A + x*Bv ; A = 1 - w*s ; Bv = 2*w*s - w
// H[b,h,e]   = prod_i (A[i,h,e] + x[b,i,e]*Bv[i,h,e])
// out[b,o,e] = 1 - prod_h (1 - dw[h,o,e]*H[b,h,e])
//
// Laws (R4-R21): (1) acc <= 32 VGPR; (2) s1's LDS x-staging is load-bearing
// (R18: removing it -> 163 us); (3) no device-scope fences; (4) >= 4
// blocks/CU; s1 frozen at R14 (sum-of-pipes, no single binding term —
// R15/R16/R17/R18 all failed); (5) XCD-L2-pinning remaps are the proven
// lever family (R13 -2, R14 -5); (6) >=32B line-clean stores (R18);
// (7) R20 LESSON (closes R12): s2's H-tile prologue needs b-tile >= 8 —
// 2-b tiles read P1 64 B per 4 KB row (line-sparse) and reproduce the
// R12 failure signature (FETCH ~55-67 MB, WRITE ~93-99 MB, s2 45-48 us)
// regardless of bit placement / thread idleness / store granularity.
// 4x line-DENSE P1 reads (R13) < 1x line-SPARSE reads (R12/R20).
// Ledger (R19-confirmed): 88.6 = fill ~43 (harness poison, IN-WINDOW,
// untouchable) + s1 ~29 + s2 ~13 + comb2 ~3.
// This round (R21): restore the R19-verified optimum byte-identical
// (R14 s1 + R13 s2 + comb2) after R20's s2 regression.
//
// ws: P1 [8][512][128][8] fp32 @ 0        (16 MB)  stage1 i-split partials
//     P2 [16][128][128][8] fp32 @ 4194304 (8 MB)   stage2 h-split partials

#define LD4(p) (*(const float4*)(p))

static __device__ __forceinline__ float4 f4mul(float4 a, float4 b) {
    return make_float4(a.x*b.x, a.y*b.y, a.z*b.z, a.w*b.w);
}
static __device__ __forceinline__ float4 f4fma(float4 a, float4 b, float4 c) {
    return make_float4(fmaf(a.x,b.x,c.x), fmaf(a.y,b.y,c.y),
                       fmaf(a.z,b.z,c.z), fmaf(a.w,b.w,c.w));
}
static __device__ __forceinline__ float4 f4nfma1(float4 d, float4 h) {  // 1-d*h
    return make_float4(fmaf(-d.x,h.x,1.0f), fmaf(-d.y,h.y,1.0f),
                       fmaf(-d.z,h.z,1.0f), fmaf(-d.w,h.w,1.0f));
}

// ---------------------------------------------------------------------------
// Stage 1 (R14, frozen). Grid 2048. Decode: bits [1:0]=hg-lo, [2]=ks-lo,
// [4:3]=hg-hi, [6:5]=ks-hi, [10:7]=bg. XCD = (hg&3)|(ks&1)<<2 -> hot cw/cs
// set 1 MB/XCD, 16x bg L2 reuse. Block 256 = 4 waves = 4 i-subchunks of 8.
// Lane = eh2 x hl32; thread tile 8b x 1h x 4e (acc = 32 VGPR).
// ---------------------------------------------------------------------------
__global__ __launch_bounds__(256, 4) void k_stage1(
    const float* __restrict__ in,   // [128][256][8]
    const float* __restrict__ cw,   // [256][512][8]
    const float* __restrict__ cs,   // [256][512][8]
    float* __restrict__ P1)         // ws: [8][512][128][8]
{
    __shared__ float lds[4096];              // 16 KB: x-tile [0,2048) then combine
    const int t    = threadIdx.x;
    const int lane = t & 63;
    const int kc   = t >> 6;                 // 0..3
    const int eh   = lane & 1;
    const int hl   = lane >> 1;              // 0..31
    const int bid  = blockIdx.x;
    const int hg   = (bid & 3) | (((bid >> 3) & 3) << 2);    // 0..15
    const int ks   = ((bid >> 2) & 1) | (((bid >> 5) & 3) << 1); // 0..7
    const int bg   = bid >> 7;                               // 0..15
    const int b0   = bg * 8;
    const int h    = hg * 32 + hl;
    const int e0   = eh * 4;

    // stage x[b0:+8][ks*32:+32][0:8] -> lds (layout [b][il][e]), coalesced
    {
        float4* xs4 = (float4*)lds;
        #pragma unroll
        for (int k = 0; k < 2; ++k) {
            const int f4  = t + k * 256;     // 0..511
            const int b   = f4 >> 6;
            const int col = f4 & 63;         // float4 within 256-float row
            xs4[f4] = LD4(in + (b0 + b) * 2048 + ks * 256 + col * 4);
        }
    }
    __syncthreads();

    const int i0 = ks * 32 + kc * 8;
    const float* pw = cw + i0 * 4096 + h * 8 + e0;
    const float* ps = cs + i0 * 4096 + h * 8 + e0;
    const float* xbase = lds + kc * 64 + e0;    // + b*256 + ii*8 (immediates)

    float4 acc[8];
    #pragma unroll
    for (int b = 0; b < 8; ++b) acc[b] = make_float4(1.f, 1.f, 1.f, 1.f);

    #pragma unroll
    for (int ii = 0; ii < 8; ++ii) {
        const float4 wv = LD4(pw);
        const float4 sv = LD4(ps);
        pw += 4096; ps += 4096;
        const float4 p  = f4mul(wv, sv);
        const float4 A  = make_float4(1.f - p.x, 1.f - p.y, 1.f - p.z, 1.f - p.w);
        const float4 Bv = make_float4(fmaf(2.f, p.x, -wv.x), fmaf(2.f, p.y, -wv.y),
                                      fmaf(2.f, p.z, -wv.z), fmaf(2.f, p.w, -wv.w));
        #pragma unroll
        for (int b = 0; b < 8; ++b) {
            const float4 xv = LD4(xbase + b * 256 + ii * 8);
            acc[b] = f4mul(acc[b], f4fma(xv, Bv, A));
        }
    }

    __syncthreads();                         // x-tile dead; reuse lds
    #pragma unroll
    for (int phase = 0; phase < 2; ++phase) {
        if (phase) __syncthreads();          // protect phase-0 reads
        #pragma unroll
        for (int j = 0; j < 4; ++j)
            *(float4*)&lds[kc * 1024 + j * 256 + hl * 8 + e0] = acc[phase * 4 + j];
        __syncthreads();
        {   // combine 4 kc; thread t -> one float4 of the 1024-float tile
            const int o4 = t * 4;            // j*256 + hl2*8 + eq*4
            float4 m = LD4(&lds[o4]);
            #pragma unroll
            for (int c = 1; c < 4; ++c) m = f4mul(m, LD4(&lds[c * 1024 + o4]));
            const int j   = o4 >> 8;
            const int hl2 = (o4 >> 3) & 31;
            const int eq  = o4 & 7;          // 0 or 4
            *(float4*)(P1 + ks * 524288 + (hg * 32 + hl2) * 1024
                          + (b0 + phase * 4 + j) * 8 + eq) = m;
        }
    }
}

// ---------------------------------------------------------------------------
// Stage 2 (R11 structure, R13 remap). Grid 1024 = ks16 (low bits:
// XCD = ks&7 pins P1 h-slices + dw slice in L2) x og4 x bg16.
// Block 256 = 4 waves; lane = eh2 x ol32; thread tile 8b x 1o x 4e.
// H-tile prologue reads P1 in 256 B dense runs (law 7).
// ---------------------------------------------------------------------------
__global__ __launch_bounds__(256, 4) void k_stage2(
    const float* __restrict__ dw,   // [512][128][8]
    const float* __restrict__ P1,   // ws: [8][512][128][8]
    float* __restrict__ P2)         // ws: [16][128][128][8]
{
    __shared__ float lds[4096];              // 16 KB: H-tile [0,2048) then combine
    const int t    = threadIdx.x;
    const int lane = t & 63;
    const int kc   = t >> 6;                 // 0..3
    const int eh   = lane & 1;
    const int ol   = lane >> 1;              // 0..31
    const int ks   = blockIdx.x & 15;        // LOW bits: XCD = ks&7
    const int og   = (blockIdx.x >> 4) & 3;
    const int bg   = blockIdx.x >> 6;        // 0..15
    const int b0   = bg * 8;
    const int o    = og * 32 + ol;
    const int e0   = eh * 4;
    const int h0   = ks * 32;

    // H-tile: product of the 8 i-split partials, layout [hl][b][e]
    {
        float4* ht4 = (float4*)lds;
        #pragma unroll
        for (int k = 0; k < 2; ++k) {
            const int f4  = t + k * 256;     // 0..511
            const int hl  = f4 >> 4;
            const int rem = f4 & 15;         // b*2 + eq
            const float* q = P1 + (h0 + hl) * 1024 + b0 * 8 + rem * 4;
            float4 m = LD4(q);
            #pragma unroll
            for (int c = 1; c < 8; ++c) m = f4mul(m, LD4(q + c * 524288));
            ht4[f4] = m;
        }
    }
    __syncthreads();

    const float* pd = dw + (h0 + kc * 8) * 1024 + o * 8 + e0;
    const float* hbase = lds + kc * 512 + e0;   // + ii*64 + b*8 (immediates)

    float4 acc[8];
    #pragma unroll
    for (int b = 0; b < 8; ++b) acc[b] = make_float4(1.f, 1.f, 1.f, 1.f);

    #pragma unroll
    for (int ii = 0; ii < 8; ++ii) {
        const float4 dv = LD4(pd);
        pd += 1024;
        #pragma unroll
        for (int b = 0; b < 8; ++b) {
            const float4 hv = LD4(hbase + ii * 64 + b * 8);
            acc[b] = f4mul(acc[b], f4nfma1(dv, hv));
        }
    }

    __syncthreads();                         // H-tile dead; reuse lds
    // 2 phases of 4 b: partial[kc][j4][ol32][e8] = 1024 floats per kc
    #pragma unroll
    for (int phase = 0; phase < 2; ++phase) {
        if (phase) __syncthreads();
        #pragma unroll
        for (int j = 0; j < 4; ++j)
            *(float4*)&lds[kc * 1024 + j * 256 + ol * 8 + e0] = acc[phase * 4 + j];
        __syncthreads();
        {
            const int o4 = t * 4;            // j*256 + ol2*8 + eq*4
            float4 m = LD4(&lds[o4]);
            #pragma unroll
            for (int c = 1; c < 4; ++c) m = f4mul(m, LD4(&lds[c * 1024 + o4]));
            const int j   = o4 >> 8;
            const int ol2 = (o4 >> 3) & 31;
            const int eq  = o4 & 7;
            *(float4*)(P2 + ks * 131072 + (b0 + phase * 4 + j) * 1024
                          + (og * 32 + ol2) * 8 + eq) = m;
        }
    }
}

// ---------------------------------------------------------------------------
// Final: out = 1 - prod over the 16 h-split partials. 8 MB read, 0.5 MB write.
// 16 independent loads per thread -> deep MLP.
// ---------------------------------------------------------------------------
__global__ __launch_bounds__(256, 4) void k_comb2(
    const float* __restrict__ P2,   // ws: [16][128][128][8]
    float* __restrict__ out)        // [128][128][8]
{
    const int idx4 = blockIdx.x * 256 + threadIdx.x;   // 0..32767
    float4 m = LD4(P2 + idx4 * 4);
    #pragma unroll
    for (int c = 1; c < 16; ++c)
        m = f4mul(m, LD4(P2 + c * 131072 + idx4 * 4));
    const float4 r = make_float4(1.f - m.x, 1.f - m.y, 1.f - m.z, 1.f - m.w);
    *(float4*)(out + idx4 * 4) = r;
}

extern "C" void kernel_launch(void* const* d_in, const int* in_sizes, int n_in,
                              void* d_out, int out_size, void* d_ws, size_t ws_size,
                              hipStream_t stream)
{
    const float* in = (const float*)d_in[0];   // [128][256][8]
    const float* cw = (const float*)d_in[1];   // [256][512][8]
    const float* cs = (const float*)d_in[2];   // [256][512][8]
    const float* dw = (const float*)d_in[3];   // [512][128][8]
    float* outp = (float*)d_out;               // [128][128][8]
    float* P1   = (float*)d_ws;                // 16 MB
    float* P2   = (float*)d_ws + 4194304;      // 8 MB

    k_stage1<<<2048, 256, 0, stream>>>(in, cw, cs, P1);
    k_stage2<<<1024, 256, 0, stream>>>(dw, P1, P2);
    k_comb2<<<128, 256, 0, stream>>>(P2, outp);
}